// Round 9
// baseline (86.725 us; speedup 1.0000x reference)
//
#include <hip/hip_runtime.h>

// ChamferLoss: B=4, N=M=8192, D=3, fp32.
// loss = mean_b[ mean(pred2gt) + mean(gt2pred) + max(pred2gt) ]
// R17: 16x16x32 MFMA restructure. R14/R16 tweaks on the 32x32 shape were both
//  neutral => its 16-reg accumulator granularity (~112 acc regs live) and
//  160-shuffle epilogue are structural. K=32 gives spare k-slots: ONE 16B
//  B-word per y-point serves both A-groups (g0: xh,1 -> xh.yh+xh.yl+y2;
//  g1: xl,0 -> xl.yh+xl.yl EXACT, term previously dropped; g2,3: A=0).
//  - acc liveness ~45 regs (mn 4xf32x4 + e 2xf32x4 + zero f32x4)
//  - LDS 32KB = whole 2048-pt slice, ONE barrier; broadcast reads, 0 conflicts
//  - epilogue butterfly halves (4 offs x 16 vals)
//  - MFMA x4 count @ ~5cyc (2560 cyc/wave) still < 1024-min3 VALU stream
//  Layouts (m89-verified family): A row=l&15, k=(l>>4)*8+e; B col=l&15 same k;
//  C/D col=l&15, row=(l>>4)*4+reg.
//  Fixed ~41us harness ws-poison fill is included in dur_us (R12 discovery).

typedef short  s16x8  __attribute__((ext_vector_type(8)));
typedef float  f32x4  __attribute__((ext_vector_type(4)));

#define BATCH 4
#define NPTS  8192
#define TPB   256
#define YS    4                    // y slices per (b,dir)
#define YPS   (NPTS / YS)          // 2048 y-points per slice
#define YT16  (YPS / 16)           // 128 y-tiles (16 pts) per slice
#define XPB   256                  // x per block: 4 waves x 4 tiles x 16
#define NXC   (NPTS / XPB)         // 32
#define RBLK  64                   // reduce blocks

__device__ __forceinline__ unsigned int bft(float f) { return __float_as_uint(f) >> 16; }
__device__ __forceinline__ float bfv(unsigned int s) { return __uint_as_float(s << 16); }

__global__ __launch_bounds__(TPB, 4)
void nn_fused(const float* __restrict__ pred, const float* __restrict__ gt,
              float* __restrict__ pmin, unsigned int* __restrict__ accum) {
    const int xc = blockIdx.x, sl = blockIdx.y, bd = blockIdx.z;
    const int t = threadIdx.x;
    // Zero reduce accumulators (8 sums + 8 maxbits + counter); stream-ordered.
    if (xc == 0 && sl == 0 && bd == 0 && t < 17) accum[t] = 0u;

    const int b = bd >> 1, dir = bd & 1;
    const float* xp = (dir ? gt : pred) + (size_t)b * NPTS * 3;
    const float* yp = (dir ? pred : gt) + (size_t)b * NPTS * 3;

    const int w = t >> 6, l = t & 63;
    const int c16 = l & 15, g = l >> 4;                // col, k/row group
    const int xbase = xc * XPB + w * 64;

    // Whole slice staged once: ldsb[pt] = B-word of y-point pt (16B each).
    __shared__ uint4 ldsb[YPS];                        // 32 KB

    // A-frags + x2 for the wave's four 16-row x-tiles.
    // g0: [xh0,xh1,xh2, xh0,xh1,xh2, 1, 1]  (pairs with B k0-7)
    // g1: [xl0,xl1,xl2, xl0,xl1,xl2, 0, 0]  (pairs with B k8-15)
    // g2,3: 0 (their B read is don't-care).
    s16x8 af[4];
    float x2j[4];
    #pragma unroll
    for (int xt = 0; xt < 4; ++xt) {
        const int xi = xbase + xt * 16 + c16;
        const float c0 = xp[xi * 3], c1 = xp[xi * 3 + 1], c2 = xp[xi * 3 + 2];
        x2j[xt] = c0 * c0 + c1 * c1 + c2 * c2;
        const unsigned int xh0 = bft(c0), xh1 = bft(c1), xh2 = bft(c2);
        const unsigned int xl0 = bft(c0 - bfv(xh0));
        const unsigned int xl1 = bft(c1 - bfv(xh1));
        const unsigned int xl2 = bft(c2 - bfv(xh2));
        const unsigned int s0 = (g == 0) ? xh0 : (g == 1 ? xl0 : 0u);
        const unsigned int s1 = (g == 0) ? xh1 : (g == 1 ? xl1 : 0u);
        const unsigned int s2 = (g == 0) ? xh2 : (g == 1 ? xl2 : 0u);
        const unsigned int s3 = (g == 0) ? 0x3F80u : 0u;   // 1.0 bf16
        s16x8 a;
        a[0] = (short)s0; a[1] = (short)s1; a[2] = (short)s2;
        a[3] = (short)s0; a[4] = (short)s1; a[5] = (short)s2;
        a[6] = (short)s3; a[7] = (short)s3;
        af[xt] = a;
    }

    // Stage: 8 y-points/thread -> one packed B-word each.
    // B col k0-15 (k8-15 identical): [-2yh0..2, -2yl0..2, y2h, y2l]
    #pragma unroll
    for (int i = 0; i < 8; ++i) {
        const int p = i * 256 + t;                     // 0..2047
        const int pt = sl * YPS + p;
        const float a0 = yp[pt * 3], a1 = yp[pt * 3 + 1], a2 = yp[pt * 3 + 2];
        const unsigned int yh0 = bft(a0), yh1 = bft(a1), yh2 = bft(a2);
        const float l0 = a0 - bfv(yh0), l1 = a1 - bfv(yh1), l2 = a2 - bfv(yh2);
        const unsigned int nh0 = bft(-2.f * bfv(yh0));  // exact in bf16
        const unsigned int nh1 = bft(-2.f * bfv(yh1));
        const unsigned int nh2 = bft(-2.f * bfv(yh2));
        const unsigned int nl0 = bft(-2.f * l0), nl1 = bft(-2.f * l1), nl2 = bft(-2.f * l2);
        const float y2 = a0 * a0 + a1 * a1 + a2 * a2;
        const unsigned int q2h = bft(y2);
        const unsigned int q2l = bft(y2 - bfv(q2h));
        uint4 w0;
        w0.x = nh0 | (nh1 << 16);
        w0.y = nh2 | (nl0 << 16);
        w0.z = nl1 | (nl2 << 16);
        w0.w = q2h | (q2l << 16);
        ldsb[p] = w0;
    }
    __syncthreads();

    f32x4 zero, mn[4];
    #pragma unroll
    for (int r = 0; r < 4; ++r) {
        zero[r] = 0.f;
        mn[0][r] = 3.4e38f; mn[1][r] = 3.4e38f; mn[2][r] = 3.4e38f; mn[3][r] = 3.4e38f;
    }

    // Hot loop: 128 y-tiles, 4/iter. Per 2 tiles: 2 broadcast ds_read_b128,
    // 8 MFMA (4 xt), 16 v_min3 (2 e-results folded per op).
    const uint4* bp = ldsb + c16;
    for (int tp = 0; tp < YT16; tp += 4) {
        #pragma unroll
        for (int u = 0; u < 2; ++u) {
            const s16x8 bfa = __builtin_bit_cast(s16x8, bp[(tp + 2 * u) * 16]);
            const s16x8 bfb = __builtin_bit_cast(s16x8, bp[(tp + 2 * u + 1) * 16]);
            #pragma unroll
            for (int xt = 0; xt < 4; ++xt) {
                const f32x4 ea = __builtin_amdgcn_mfma_f32_16x16x32_bf16(af[xt], bfa, zero, 0, 0, 0);
                const f32x4 eb = __builtin_amdgcn_mfma_f32_16x16x32_bf16(af[xt], bfb, zero, 0, 0, 0);
                #pragma unroll
                for (int r = 0; r < 4; ++r)
                    mn[xt][r] = fminf(fminf(mn[xt][r], ea[r]), eb[r]);
            }
        }
    }

    // Butterfly min across the 16 cols (y) within each 16-lane group.
    #pragma unroll
    for (int off = 8; off; off >>= 1) {
        #pragma unroll
        for (int xt = 0; xt < 4; ++xt)
            #pragma unroll
            for (int r = 0; r < 4; ++r)
                mn[xt][r] = fminf(mn[xt][r], __shfl_xor(mn[xt][r], off, 64));
    }

    // Lane (g, c16): holds y-min for x-row g*4+r of each xt, replicated over
    // c16. Lanes with c16<4 store row g*4 + c16 (value mn[xt][c16]).
    const int cr = l & 3;
    const float x2s0 = __shfl(x2j[0], g * 4 + cr, 64);
    const float x2s1 = __shfl(x2j[1], g * 4 + cr, 64);
    const float x2s2 = __shfl(x2j[2], g * 4 + cr, 64);
    const float x2s3 = __shfl(x2j[3], g * 4 + cr, 64);
    if (c16 < 4) {
        float v0 = mn[0][0], v1 = mn[1][0], v2 = mn[2][0], v3 = mn[3][0];
        #pragma unroll
        for (int rr = 1; rr < 4; ++rr) {
            v0 = (cr == rr) ? mn[0][rr] : v0;
            v1 = (cr == rr) ? mn[1][rr] : v1;
            v2 = (cr == rr) ? mn[2][rr] : v2;
            v3 = (cr == rr) ? mn[3][rr] : v3;
        }
        float* dst = pmin + ((size_t)bd * YS + sl) * NPTS + xbase + g * 4 + cr;
        dst[0]  = fmaxf(v0 + x2s0, 0.f);
        dst[16] = fmaxf(v1 + x2s1, 0.f);
        dst[32] = fmaxf(v2 + x2s2, 0.f);
        dst[48] = fmaxf(v3 + x2s3, 0.f);
    }
}

// 64 blocks x 256 threads. Block g: bd = g>>3, x-segment = g&7 (1024 pts).
// Min over YS slices, partial sum+max per block -> device atomics; last
// block finalizes out[0]. accum: [0..7] f32 sums, [8..15] u32 maxbits, [16] ctr.
__global__ __launch_bounds__(TPB)
void reduce_all(const float* __restrict__ pmin, float* __restrict__ accum,
                float* __restrict__ out) {
    const int g = blockIdx.x, bd = g >> 3, seg = g & 7;
    const int t = threadIdx.x;
    const float4* base = (const float4*)(pmin + (size_t)bd * YS * NPTS);
    const int f4 = seg * 256 + t;                      // float4 idx within slice
    float4 q = base[f4];
    #pragma unroll
    for (int sl = 1; sl < YS; ++sl) {
        const float4 rr = base[sl * (NPTS / 4) + f4];
        q.x = fminf(q.x, rr.x); q.y = fminf(q.y, rr.y);
        q.z = fminf(q.z, rr.z); q.w = fminf(q.w, rr.w);
    }
    float s = (q.x + q.y) + (q.z + q.w);
    float m = fmaxf(fmaxf(q.x, q.y), fmaxf(q.z, q.w));
    #pragma unroll
    for (int off = 32; off; off >>= 1) {
        s += __shfl_down(s, off, 64);
        m = fmaxf(m, __shfl_down(m, off, 64));
    }
    __shared__ float ws_[4], wm_[4];
    if ((t & 63) == 0) { ws_[t >> 6] = s; wm_[t >> 6] = m; }
    __syncthreads();
    if (t == 0) {
        s = (ws_[0] + ws_[1]) + (ws_[2] + ws_[3]);
        m = fmaxf(fmaxf(wm_[0], wm_[1]), fmaxf(wm_[2], wm_[3]));
        atomicAdd(&accum[bd], s);
        atomicMax((unsigned int*)accum + 8 + bd, __float_as_uint(m));  // d>=0
        __threadfence();
        const unsigned int done = atomicAdd((unsigned int*)accum + 16, 1u);
        if (done == RBLK - 1) {
            float acc = 0.f;
            #pragma unroll
            for (int b2 = 0; b2 < BATCH; ++b2) {
                const float s0 = atomicAdd(&accum[2 * b2], 0.f);      // coherent read
                const float s1 = atomicAdd(&accum[2 * b2 + 1], 0.f);
                const unsigned int mb =
                    atomicMax((unsigned int*)accum + 8 + 2 * b2, 0u); // pred2gt max
                acc += (s0 + s1) * (1.f / NPTS) + __uint_as_float(mb);
            }
            out[0] = acc * (1.f / BATCH);
        }
    }
}

extern "C" void kernel_launch(void* const* d_in, const int* in_sizes, int n_in,
                              void* d_out, int out_size, void* d_ws, size_t ws_size,
                              hipStream_t stream) {
    const float* pred = (const float*)d_in[0];
    const float* gt   = (const float*)d_in[1];

    float* pmin = (float*)d_ws;                        // 8 * 4 * 8192 * 4B = 1 MB
    float* accum = (float*)((char*)d_ws + (size_t)2 * BATCH * YS * NPTS * 4);

    dim3 g1(NXC, YS, 2 * BATCH);   // 32 x 4 x 8 = 1024 blocks
    nn_fused<<<g1, TPB, 0, stream>>>(pred, gt, pmin, (unsigned int*)accum);
    reduce_all<<<dim3(RBLK), TPB, 0, stream>>>(pmin, accum, (float*)d_out);
}

// Round 11
// 76.291 us; speedup vs baseline: 1.1368x; 1.1368x over previous
//
#include <hip/hip_runtime.h>

// ChamferLoss: B=4, N=M=8192, D=3, fp32.
// loss = mean_b[ mean(pred2gt) + mean(gt2pred) + max(pred2gt) ]
// R19 = R18 resubmitted (acquisition timeout; unmeasured), with one de-risk
//  fix: R18's "64KB" LDS was actually 128KB static (PHT=128). Now 4 phases x
//  2048 pts = 64KB static LDS, same experiment otherwise.
// R18 rationale: back to 32x32x16 (R17's 16x16 shape DOUBLED matrix-pipe time:
//  844 FLOP/SIMD-cyc vs 990, half of K wasted -> +4.6us measured). Floor =
//  6.9us matrix; measured ~30 => ~75% stall; MfmaUtil==work/time every round.
//  - one-pair-behind fold (ping-pong pA/pB,qA/qB): min3 reads results >=2
//    MFMAs (>=64 matrix-cyc) old -> no MFMA-result-latency stall;
//  - TPB=512, J=1: 256 blocks (1/CU, 2 waves/SIMD, ~256-reg budget/wave),
//    each wave = one 32-x tile over ALL 8192 y; mn = one f32x16; butterfly
//    halves vs R12 (80 shuffles);
//  - d final in-block -> block sum/max -> 2KB partials + 1-block micro-reduce;
//    pmin array + big reduce dispatch deleted.
//  Fixed ~40.5us harness ws-poison fill is included in dur_us (R12 discovery).
//   A row m (K=16): [xh0..2, xh0..2, xl0,xl1 | xl2, 1, 1, 0...]
//   B col n (K=16): [-2yh0..2, -2yl0..2, -2yh0,-2yh1 | -2yh2, y2h, y2l, 0...]
//   D = y2 - 2(xh.yh + xh.yl + xl.yh); d2 = x2 + min_y D  (xl.yl ~2^-18 dropped)

typedef short  s16x8  __attribute__((ext_vector_type(8)));
typedef float  f32x16 __attribute__((ext_vector_type(16)));

#define BATCH 4
#define NPTS  8192
#define TPB   512                  // 8 waves; 1 block/CU; 2 waves/SIMD
#define XPB   256                  // x per block: 8 waves x 1 tile x 32
#define NXC   (NPTS / XPB)         // 32
#define NPH   4                    // stage phases
#define PHPTS (NPTS / NPH)         // 2048 y-points per phase (64 KB LDS)
#define PHT   (PHPTS / 32)         // 64 y-tiles per phase

__device__ __forceinline__ unsigned int bft(float f) { return __float_as_uint(f) >> 16; }
__device__ __forceinline__ float bfv(unsigned int s) { return __uint_as_float(s << 16); }

__global__ __launch_bounds__(TPB, 2)
void nn_fused(const float* __restrict__ pred, const float* __restrict__ gt,
              float2* __restrict__ partials) {
    const int xc = blockIdx.x, bd = blockIdx.z;
    const int b = bd >> 1, dir = bd & 1;
    const float* xp = (dir ? gt : pred) + (size_t)b * NPTS * 3;
    const float* yp = (dir ? pred : gt) + (size_t)b * NPTS * 3;

    const int t = threadIdx.x;
    const int wv = t >> 6, l = t & 63;
    const int m32 = l & 31, hh = l >> 5;

    // [tile(64)][{0..31: w0(k0-7), 32..63: w1(k8-15)}] per phase = 64 KB
    __shared__ uint4 ldsb[PHT * 64];

    // A-frag + x2 for the wave's single 32-row x-tile.
    const int xi = xc * XPB + wv * 32 + m32;
    const float c0 = xp[xi * 3], c1 = xp[xi * 3 + 1], c2 = xp[xi * 3 + 2];
    const float x2 = c0 * c0 + c1 * c1 + c2 * c2;
    s16x8 af;
    {
        const unsigned int xh0 = bft(c0), xh1 = bft(c1), xh2 = bft(c2);
        const unsigned int xl0 = bft(c0 - bfv(xh0));
        const unsigned int xl1 = bft(c1 - bfv(xh1));
        const unsigned int xl2 = bft(c2 - bfv(xh2));
        af[0] = (short)(hh ? xl2 : xh0);
        af[1] = (short)(hh ? 0x3F80u : xh1);           // 1.0 bf16 (y2h)
        af[2] = (short)(hh ? 0x3F80u : xh2);           // 1.0 bf16 (y2l)
        af[3] = (short)(hh ? 0u : xh0);
        af[4] = (short)(hh ? 0u : xh1);
        af[5] = (short)(hh ? 0u : xh2);
        af[6] = (short)(hh ? 0u : xl0);
        af[7] = (short)(hh ? 0u : xl1);
    }

    f32x16 zero, mn;
    #pragma unroll
    for (int r = 0; r < 16; ++r) { zero[r] = 0.f; mn[r] = 3.4e38f; }

    const uint4* bp = ldsb + l;                        // lane's fixed k-half slot

#define FOLD(EA, EB)                                                                  \
    do { _Pragma("unroll")                                                            \
         for (int r = 0; r < 16; ++r)                                                 \
             mn[r] = fminf(fminf(mn[r], (EA)[r]), (EB)[r]); } while (0)
#define MFMA(BF) __builtin_amdgcn_mfma_f32_32x32x16_bf16(af, (BF), zero, 0, 0, 0)

    for (int ph = 0; ph < NPH; ++ph) {
        if (ph) __syncthreads();                       // prev-phase reads done
        // Stage 2048 y-points (4/thread) -> packed B-frags in LDS.
        #pragma unroll
        for (int i = 0; i < PHPTS / TPB; ++i) {
            const int q = i * TPB + t;                 // 0..2047 within phase
            const int pt = ph * PHPTS + q;
            const float a0 = yp[pt * 3], a1 = yp[pt * 3 + 1], a2 = yp[pt * 3 + 2];
            const unsigned int yh0 = bft(a0), yh1 = bft(a1), yh2 = bft(a2);
            const float l0 = a0 - bfv(yh0), l1 = a1 - bfv(yh1), l2 = a2 - bfv(yh2);
            const unsigned int nh0 = bft(-2.f * bfv(yh0));  // exact in bf16
            const unsigned int nh1 = bft(-2.f * bfv(yh1));
            const unsigned int nh2 = bft(-2.f * bfv(yh2));
            const unsigned int nl0 = bft(-2.f * l0), nl1 = bft(-2.f * l1), nl2 = bft(-2.f * l2);
            const float y2 = a0 * a0 + a1 * a1 + a2 * a2;
            const unsigned int q2h = bft(y2);
            const unsigned int q2l = bft(y2 - bfv(q2h));
            uint4 w0, w1;
            w0.x = nh0 | (nh1 << 16);
            w0.y = nh2 | (nl0 << 16);
            w0.z = nl1 | (nl2 << 16);
            w0.w = nh0 | (nh1 << 16);
            w1.x = nh2 | (q2h << 16);
            w1.y = q2l;
            w1.z = 0u; w1.w = 0u;
            ldsb[(q >> 5) * 64 + (q & 31)]      = w0;
            ldsb[(q >> 5) * 64 + 32 + (q & 31)] = w1;
        }
        __syncthreads();

        // Hot loop: 64 tiles, one-pair-behind fold (ping-pong, no rotate).
        f32x16 pA, pB, qA, qB;
        {
            const s16x8 b0 = __builtin_bit_cast(s16x8, bp[0]);
            const s16x8 b1 = __builtin_bit_cast(s16x8, bp[64]);
            pA = MFMA(b0); pB = MFMA(b1);
        }
        for (int i = 2; i < PHT - 2; i += 4) {
            {
                const s16x8 b0 = __builtin_bit_cast(s16x8, bp[i * 64]);
                const s16x8 b1 = __builtin_bit_cast(s16x8, bp[(i + 1) * 64]);
                qA = MFMA(b0); qB = MFMA(b1);
                FOLD(pA, pB);                          // results >=2 MFMAs old
            }
            {
                const s16x8 b0 = __builtin_bit_cast(s16x8, bp[(i + 2) * 64]);
                const s16x8 b1 = __builtin_bit_cast(s16x8, bp[(i + 3) * 64]);
                pA = MFMA(b0); pB = MFMA(b1);
                FOLD(qA, qB);
            }
        }
        {   // tail tiles PHT-2, PHT-1
            const s16x8 b0 = __builtin_bit_cast(s16x8, bp[(PHT - 2) * 64]);
            const s16x8 b1 = __builtin_bit_cast(s16x8, bp[(PHT - 1) * 64]);
            qA = MFMA(b0); qB = MFMA(b1);
            FOLD(pA, pB);
            FOLD(qA, qB);
        }
    }
#undef MFMA
#undef FOLD

    // Butterfly min across the 32 cols (stays within each 32-lane half).
    #pragma unroll
    for (int off = 16; off; off >>= 1)
        #pragma unroll
        for (int r = 0; r < 16; ++r)
            mn[r] = fminf(mn[r], __shfl_xor(mn[r], off, 64));

    // Lane l (r = l&15): holds col-min for row (r&3)+8*(r>>2)+4*hh.
    const int r = l & 15;
    const int row = (r & 3) + 8 * (r >> 2) + 4 * hh;   // C/D row map (m74/m101)
    float v = mn[0];
    #pragma unroll
    for (int rr = 1; rr < 16; ++rr) v = (r == rr) ? mn[rr] : v;
    const float x2s = __shfl(x2, row, 64);
    const bool valid = (l & 31) < 16;
    const float d = valid ? fmaxf(v + x2s, 0.f) : 0.f;

    // Block reduction: sum + max over the block's 256 final d's.
    float s = d, m = valid ? d : -1.f;
    #pragma unroll
    for (int off = 32; off; off >>= 1) {
        s += __shfl_xor(s, off, 64);
        m = fmaxf(m, __shfl_xor(m, off, 64));
    }
    __shared__ float ws_[8], wm_[8];
    if (l == 0) { ws_[wv] = s; wm_[wv] = m; }
    __syncthreads();
    if (t == 0) {
        float bs = 0.f, bm = -1.f;
        #pragma unroll
        for (int i = 0; i < 8; ++i) { bs += ws_[i]; bm = fmaxf(bm, wm_[i]); }
        partials[bd * NXC + xc] = make_float2(bs, bm);
    }
}

// One block, 256 threads: t -> (bd = t>>5, xc = t&31). Reduce 32 partials per
// bd within each 32-lane group, then thread 0 combines 8 bd's.
__global__ __launch_bounds__(256)
void reduce_all(const float2* __restrict__ partials, float* __restrict__ out) {
    const int t = threadIdx.x;
    const float2 p = partials[t];
    float s = p.x, m = p.y;
    #pragma unroll
    for (int off = 16; off; off >>= 1) {               // stays within 32-group
        s += __shfl_xor(s, off, 64);
        m = fmaxf(m, __shfl_xor(m, off, 64));
    }
    __shared__ float s8[8], m8[8];
    if ((t & 31) == 0) { s8[t >> 5] = s; m8[t >> 5] = m; }
    __syncthreads();
    if (t == 0) {
        float acc = 0.f;
        #pragma unroll
        for (int b2 = 0; b2 < BATCH; ++b2)
            acc += (s8[2 * b2] + s8[2 * b2 + 1]) * (1.f / NPTS)
                 + m8[2 * b2];                         // max only for pred2gt
        out[0] = acc * (1.f / BATCH);
    }
}

extern "C" void kernel_launch(void* const* d_in, const int* in_sizes, int n_in,
                              void* d_out, int out_size, void* d_ws, size_t ws_size,
                              hipStream_t stream) {
    const float* pred = (const float*)d_in[0];
    const float* gt   = (const float*)d_in[1];

    float2* partials = (float2*)d_ws;                  // 256 * 8 B = 2 KB

    dim3 g1(NXC, 1, 2 * BATCH);    // 32 x 1 x 8 = 256 blocks (1/CU)
    nn_fused<<<g1, TPB, 0, stream>>>(pred, gt, partials);
    reduce_all<<<dim3(1), 256, 0, stream>>>(partials, (float*)d_out);
}